// Round 14
// baseline (154.275 us; speedup 1.0000x reference)
//
#include <hip/hip_runtime.h>
#include <stdint.h>

// Problem constants
#define T_  4096
#define B_  64
#define DI_ 64
#define DH_ 512
#define DO_ 64
#define L_  64          // chunk length
#define C_  (T_ / L_)   // 64 chunks

typedef __attribute__((ext_vector_type(8))) short bf16x8;
typedef __attribute__((ext_vector_type(2))) float f32x2;
typedef __attribute__((ext_vector_type(4))) float f32x4;
typedef __attribute__((ext_vector_type(8))) float f32x8;
typedef __attribute__((ext_vector_type(2))) __bf16 bfv2;
typedef __attribute__((ext_vector_type(4))) __bf16 bfv4;
typedef __attribute__((ext_vector_type(8))) __bf16 bfv8;

union U8 { uint4 q; bf16x8 v; bfv8 b; };
union U2 { unsigned u; bfv2 b; };

__device__ inline unsigned short f2b_rne(float f) {
    unsigned u = __float_as_uint(f);
    return (unsigned short)((u + 0x7fffu + ((u >> 16) & 1u)) >> 16);
}

// trunc-split 8 f32 -> hi bf16x8 + lo bf16x8 (combined rel err ~2^-16)
__device__ inline void trunc_split8(const float4 v0, const float4 v1, U8& hi, U8& lo) {
    const unsigned u0 = __float_as_uint(v0.x), u1 = __float_as_uint(v0.y),
                   u2 = __float_as_uint(v0.z), u3 = __float_as_uint(v0.w),
                   u4 = __float_as_uint(v1.x), u5 = __float_as_uint(v1.y),
                   u6 = __float_as_uint(v1.z), u7 = __float_as_uint(v1.w);
    hi.q.x = __builtin_amdgcn_perm(u1, u0, 0x07060302u);
    hi.q.y = __builtin_amdgcn_perm(u3, u2, 0x07060302u);
    hi.q.z = __builtin_amdgcn_perm(u5, u4, 0x07060302u);
    hi.q.w = __builtin_amdgcn_perm(u7, u6, 0x07060302u);
    const unsigned l0 = __float_as_uint(v0.x - __uint_as_float(u0 & 0xffff0000u));
    const unsigned l1 = __float_as_uint(v0.y - __uint_as_float(u1 & 0xffff0000u));
    const unsigned l2 = __float_as_uint(v0.z - __uint_as_float(u2 & 0xffff0000u));
    const unsigned l3 = __float_as_uint(v0.w - __uint_as_float(u3 & 0xffff0000u));
    const unsigned l4 = __float_as_uint(v1.x - __uint_as_float(u4 & 0xffff0000u));
    const unsigned l5 = __float_as_uint(v1.y - __uint_as_float(u5 & 0xffff0000u));
    const unsigned l6 = __float_as_uint(v1.z - __uint_as_float(u6 & 0xffff0000u));
    const unsigned l7 = __float_as_uint(v1.w - __uint_as_float(u7 & 0xffff0000u));
    lo.q.x = __builtin_amdgcn_perm(l1, l0, 0x07060302u);
    lo.q.y = __builtin_amdgcn_perm(l3, l2, 0x07060302u);
    lo.q.z = __builtin_amdgcn_perm(l5, l4, 0x07060302u);
    lo.q.w = __builtin_amdgcn_perm(l7, l6, 0x07060302u);
}

// ---------------------------------------------------------------------------
// k_frags: (A) bhi/be1/be2 frags for k_rg (t<32768, unchanged layout);
// (B) CwE hi/lo frags for k_E: B[h][n] = a_h * u_h^m/m! * c[h][o], n = m*64+o.
// Layout [kb16][nt12][lane][8]. grid 384 x 256 (=98304 threads).
// ---------------------------------------------------------------------------
__global__ __launch_bounds__(256) void k_frags(
    const float* __restrict__ bmat, const float* __restrict__ cmat,
    const float* __restrict__ a,
    unsigned short* __restrict__ bhi, unsigned short* __restrict__ be1,
    unsigned short* __restrict__ be2,
    unsigned short* __restrict__ CwEh, unsigned short* __restrict__ CwEl)
{
    const int t = blockIdx.x * 256 + threadIdx.x;   // 0..98303
    if (t < 32768) {
        const int j = t & 7, n = (t >> 3) & 15, g = (t >> 7) & 3;
        const int nt = (t >> 9) & 31, kb = (t >> 14) & 1;
        const int h = nt * 16 + n;
        const float v = bmat[(size_t)(kb * 32 + g * 8 + j) * DH_ + h];
        const float u = logf(a[h]);
        bhi[t] = f2b_rne(v);
        be1[t] = f2b_rne(v * u);
        be2[t] = f2b_rne(v * u * u * 0.5f);
    }
    {
        const int j = t & 7;
        const int lane = (t >> 3) & 63;
        const int rem = t >> 9;             // 0..191
        const int nt = rem % 12, kb = rem / 12;
        const int h = kb * 32 + (lane >> 4) * 8 + j;
        const int n = nt * 16 + (lane & 15);
        const int m = n >> 6, o = n & 63;
        const float av = a[h];
        const float u = logf(av);
        const float w = (m == 0) ? av : ((m == 1) ? av * u : av * u * u * 0.5f);
        const float v = w * cmat[(size_t)h * DO_ + o];
        unsigned short hi16 = (unsigned short)(__float_as_uint(v) >> 16);
        float lo = v - __uint_as_float(((unsigned)hi16) << 16);
        CwEh[t] = hi16;
        CwEl[t] = (unsigned short)(__float_as_uint(lo) >> 16);
    }
}

// ---------------------------------------------------------------------------
// k_D: D_p[i][o] = sum_h b[i,h] * (u_h^p/p!) * c[h,o], stored as bf16 frags
// Dstk [kb6][nt4][lane][8] with k-slot permutation: kpos<128 -> (i=kpos>>1,
// p=kpos&1); kpos in [128,192) -> p=2, i=kpos-128. grid 192 x 64.
// ---------------------------------------------------------------------------
__global__ __launch_bounds__(64) void k_D(
    const float* __restrict__ bmat, const float* __restrict__ cmat,
    const float* __restrict__ a, unsigned short* __restrict__ Dstk)
{
    const int kpos = blockIdx.x;   // 0..191
    const int o = threadIdx.x;     // 0..63
    int p, i;
    if (kpos < 128) { i = kpos >> 1; p = kpos & 1; }
    else            { p = 2; i = kpos - 128; }

    float acc = 0.f;
    for (int h = 0; h < DH_; ++h) {
        const float bv = bmat[(size_t)i * DH_ + h];
        float wp = 1.f;
        if (p > 0) {
            const float u = logf(a[h]);
            wp = (p == 1) ? u : u * u * 0.5f;
        }
        acc = fmaf(bv * wp, cmat[(size_t)h * DO_ + o], acc);
    }
    const int kb = kpos >> 5, g = (kpos >> 3) & 3, j = kpos & 7;
    const int nt = o >> 4, lm = o & 15;
    Dstk[((size_t)(kb * 4 + nt) * 64 + g * 16 + lm) * 8 + j] = f2b_rne(acc);
}

// ---------------------------------------------------------------------------
// k_mom: per-chunk moment reduction over x (streaming).
// X_k[c][k][bb*64+i] = sum_s (63-s)^k x[c*64+s][bb][i], k=0,1,2 (bf16).
// ---------------------------------------------------------------------------
__global__ __launch_bounds__(256) void k_mom(
    const float* __restrict__ x, unsigned short* __restrict__ Xm)
{
    const int c   = blockIdx.x;
    const int idx = blockIdx.y * 256 + threadIdx.x;
    const float* xp = x + (size_t)c * 64 * 4096 + idx;

    float m0 = 0.f, m1 = 0.f, m2 = 0.f;
#pragma unroll
    for (int s = 0; s < 64; ++s) {
        const float v = xp[(size_t)s * 4096];
        const float t = (float)(63 - s);
        m0 += v;
        m1 = fmaf(t, v, m1);
        m2 = fmaf(t * t, v, m2);
    }
    __bf16* Xb = (__bf16*)Xm;
    Xb[(size_t)(c * 3 + 0) * 4096 + idx] = (__bf16)m0;
    Xb[(size_t)(c * 3 + 1) * 4096 + idx] = (__bf16)m1;
    Xb[(size_t)(c * 3 + 2) * 4096 + idx] = (__bf16)m2;
}

// ---------------------------------------------------------------------------
// k_rg: r[c][bb][h] = sum_k (u^k/k!)(X_k @ b)[h], one GEMM K=192 folded.
// ---------------------------------------------------------------------------
__global__ __launch_bounds__(512) void k_rg(
    const unsigned short* __restrict__ Xm,
    const unsigned short* __restrict__ bhi, const unsigned short* __restrict__ be1,
    const unsigned short* __restrict__ be2,
    float* __restrict__ r)
{
    const int c    = blockIdx.x;
    const int nh   = blockIdx.y;
    const int tid  = threadIdx.x;
    const int lane = tid & 63;
    const int w    = tid >> 6;
    const int lm   = lane & 15;
    const int lg   = lane >> 4;

    bf16x8 af[4][6];
#pragma unroll
    for (int mt = 0; mt < 4; ++mt)
#pragma unroll
        for (int kb = 0; kb < 6; ++kb) {
            const int mom = kb >> 1;
            af[mt][kb] = *(const bf16x8*)(Xm + (size_t)(c * 3 + mom) * 4096
                                          + (mt * 16 + lm) * 64 + (kb & 1) * 32 + lg * 8);
        }

    bf16x8 bfr[6][2];
#pragma unroll
    for (int kb = 0; kb < 6; ++kb) {
        const int mom = kb >> 1;
        const unsigned short* base = (mom == 0) ? bhi : (mom == 1) ? be1 : be2;
#pragma unroll
        for (int nt = 0; nt < 2; ++nt) {
            const int ntg = nh * 16 + w * 2 + nt;
            bfr[kb][nt] = *(const bf16x8*)(base + ((size_t)((kb & 1) * 32 + ntg) * 64 + lane) * 8);
        }
    }

    f32x4 acc[4][2];
#pragma unroll
    for (int mt = 0; mt < 4; ++mt)
#pragma unroll
        for (int nt = 0; nt < 2; ++nt) acc[mt][nt] = (f32x4){0.f, 0.f, 0.f, 0.f};

#pragma unroll
    for (int kb = 0; kb < 6; ++kb)
#pragma unroll
        for (int nt = 0; nt < 2; ++nt)
#pragma unroll
            for (int mt = 0; mt < 4; ++mt)
                acc[mt][nt] = __builtin_amdgcn_mfma_f32_16x16x32_bf16(af[mt][kb], bfr[kb][nt], acc[mt][nt], 0, 0, 0);

#pragma unroll
    for (int mt = 0; mt < 4; ++mt)
#pragma unroll
        for (int nt = 0; nt < 2; ++nt)
#pragma unroll
            for (int rg = 0; rg < 4; ++rg) {
                const int bb = mt * 16 + lg * 4 + rg;
                const int h  = nh * 256 + w * 32 + nt * 16 + lm;
                r[((size_t)c * B_ + bb) * DH_ + h] = acc[mt][nt][rg];
            }
}

// ---------------------------------------------------------------------------
// k_scan: sequential scan over chunk aggregates, IN PLACE (r becomes Hst).
// ---------------------------------------------------------------------------
__global__ __launch_bounds__(512) void k_scan(
    const float* __restrict__ h0, const float* __restrict__ a,
    float* __restrict__ r, float* __restrict__ hfin)
{
    const int bb  = blockIdx.x;
    const int hid = threadIdx.x;
    const size_t base = (size_t)bb * DH_ + hid;

    float rv[C_];
#pragma unroll
    for (int c = 0; c < C_; ++c) rv[c] = r[(size_t)c * B_ * DH_ + base];

    float h  = h0[base];
    float aL = a[hid];
#pragma unroll
    for (int q = 0; q < 6; ++q) aL = aL * aL;   // a^64

#pragma unroll
    for (int c = 0; c < C_; ++c) {
        r[(size_t)c * B_ * DH_ + base] = h;      // Hst[c]
        h = fmaf(h, aL, rv[c]);
    }
    hfin[base] = h;
}

// ---------------------------------------------------------------------------
// k_E: E[(c*64+bb)][n] = Hst row @ CwE  (M=4096, N=192, K=512), hi/lo 3-term
// for fp32-grade accuracy. grid (C_, 3 n-blocks) x 512.
// ---------------------------------------------------------------------------
__global__ __launch_bounds__(512) void k_E(
    const float* __restrict__ Hst,
    const unsigned short* __restrict__ CwEh, const unsigned short* __restrict__ CwEl,
    float* __restrict__ E)
{
    const int c    = blockIdx.x;
    const int nb   = blockIdx.y;            // 0..2
    const int tid  = threadIdx.x;
    const int lane = tid & 63;
    const int w    = tid >> 6;
    const int lm   = lane & 15;
    const int lg   = lane >> 4;
    const int mt   = w >> 1;                // 4 row-tiles (bb)
    const int ntp  = (w & 1) * 2;           // 2 n-tiles per wave

    f32x4 acc[2] = {{0.f,0.f,0.f,0.f},{0.f,0.f,0.f,0.f}};

    for (int kb = 0; kb < 16; ++kb) {
        const float* ap = Hst + (size_t)(c * 64 + mt * 16 + lm) * DH_ + kb * 32 + lg * 8;
        U8 ahi, alo;
        trunc_split8(*(const float4*)ap, *(const float4*)(ap + 4), ahi, alo);
#pragma unroll
        for (int ntl = 0; ntl < 2; ++ntl) {
            const int ntg = nb * 4 + ntp + ntl;
            const size_t fo = ((size_t)(kb * 12 + ntg) * 64 + lane) * 8;
            const bf16x8 bh = *(const bf16x8*)(CwEh + fo);
            const bf16x8 bl = *(const bf16x8*)(CwEl + fo);
            acc[ntl] = __builtin_amdgcn_mfma_f32_16x16x32_bf16(ahi.v, bh, acc[ntl], 0, 0, 0);
            acc[ntl] = __builtin_amdgcn_mfma_f32_16x16x32_bf16(alo.v, bh, acc[ntl], 0, 0, 0);
            acc[ntl] = __builtin_amdgcn_mfma_f32_16x16x32_bf16(ahi.v, bl, acc[ntl], 0, 0, 0);
        }
    }

#pragma unroll
    for (int ntl = 0; ntl < 2; ++ntl)
#pragma unroll
        for (int rg = 0; rg < 4; ++rg) {
            const int row = mt * 16 + lg * 4 + rg;           // bb
            const int n   = (nb * 4 + ntp + ntl) * 16 + lm;  // 0..191
            E[(size_t)(c * 64 + row) * 192 + n] = acc[ntl][rg];
        }
}

// ---------------------------------------------------------------------------
// k_y: per (chunk, batch) block, 512 threads, static LDS 40960 B -> 3 blk/CU.
//  ph1: stage x [64][64] f32 (XOR'd 8-col blocks for conflict-free column read)
//  ph2 (wave 0): 64-step prefix scan of S0,S1,S2 over x columns; emit
//    A0=S0, A1=s*S0-S1, A2=s^2*S0-2s*S1+S2 as bf16 into swizzled A-tile
//    [64 s][192 k] (k<128: pair-slots (A0,A1); k>=128: A2).
//  ph3: y = A @ Dstk (K=192, 6 kb, 2 m-tiles x 1 o-quarter per wave) +
//    epilogue E0 + s*E1 + s^2*E2 (per-chunk H-term, from k_E).
// ---------------------------------------------------------------------------
__global__ __launch_bounds__(512, 6) void k_y(
    const float* __restrict__ x,
    const unsigned short* __restrict__ Dstk,
    const float* __restrict__ E,
    float* __restrict__ y)
{
    __shared__ __align__(16) float xs[64 * 64];            // 16384 B
    __shared__ __align__(16) unsigned short At[64 * 192];  // 24576 B

    const int c    = blockIdx.x;
    const int bb   = blockIdx.y;
    const int tid  = threadIdx.x;
    const int lane = tid & 63;
    const int w    = tid >> 6;
    const int lm   = lane & 15;
    const int lg   = lane >> 4;
    const int mp   = w >> 2;
    const int oq   = w & 3;
    const int o    = oq * 16 + lm;

    // E-term preload (row uniform per block)
    const size_t erow = (size_t)(c * 64 + bb) * 192;
    const float e0 = E[erow + o];
    const float e1 = E[erow + 64 + o];
    const float e2 = E[erow + 128 + o];

    // ---- ph1: stage x chunk ----
    {
        const int row = tid >> 3;
        const int c8  = (tid & 7) * 8;
        const int c8x = c8 ^ ((row & 3) << 3);
        const float* gp = x + (((size_t)(c * 64 + row) * 64) + bb) * 64 + c8;
        const float4 v0 = *(const float4*)gp;
        const float4 v1 = *(const float4*)(gp + 4);
        *(float4*)&xs[row * 64 + c8x]     = v0;
        *(float4*)&xs[row * 64 + c8x + 4] = v1;
    }
    __syncthreads();

    // ---- ph2: prefix-moment scan (wave 0 only) ----
    if (tid < 64) {
        const int i = tid;
        float S0 = 0.f, S1 = 0.f, S2 = 0.f;
        char* Ab = (char*)At;
#pragma unroll
        for (int s = 0; s < 64; ++s) {
            const float v = xs[s * 64 + (i ^ ((s & 3) << 3))];
            const float sf = (float)s;
            S0 += v;
            S1 = fmaf(sf, v, S1);
            S2 = fmaf(sf * sf, v, S2);
            const float A0 = S0;
            const float A1 = fmaf(sf, S0, -S1);
            const float A2 = fmaf(sf, fmaf(sf, S0, -2.0f * S1), S2);
            const int f = (s & 7) << 4;
            U2 pk; pk.b = __builtin_convertvector((f32x2){A0, A1}, bfv2);
            *(unsigned*)(Ab + ((s * 384 + 4 * i) ^ f)) = pk.u;
            *(__bf16*)(Ab + ((s * 384 + 256 + 2 * i) ^ f)) = (__bf16)A2;
        }
    }
    __syncthreads();

    // ---- ph3: y = A @ D + E-term ----
    {
        const int row0 = (mp * 2 + 0) * 16 + lm;
        const int row1 = (mp * 2 + 1) * 16 + lm;
        const int f0 = (row0 & 7) << 4;
        const int f1 = (row1 & 7) << 4;
        const char* Ab = (const char*)At;

        f32x4 acc0 = {0.f, 0.f, 0.f, 0.f};
        f32x4 acc1 = {0.f, 0.f, 0.f, 0.f};

        __builtin_amdgcn_s_setprio(1);
#pragma unroll
        for (int kb = 0; kb < 6; ++kb) {
            const int b2k = kb * 64 + lg * 16;   // byte offset of k0*2
            const bf16x8 a0 = *(const bf16x8*)(Ab + ((row0 * 384 + b2k) ^ f0));
            const bf16x8 a1 = *(const bf16x8*)(Ab + ((row1 * 384 + b2k) ^ f1));
            const bf16x8 df = *(const bf16x8*)(Dstk + ((size_t)(kb * 4 + oq) * 64 + lane) * 8);
            acc0 = __builtin_amdgcn_mfma_f32_16x16x32_bf16(a0, df, acc0, 0, 0, 0);
            acc1 = __builtin_amdgcn_mfma_f32_16x16x32_bf16(a1, df, acc1, 0, 0, 0);
        }
        __builtin_amdgcn_s_setprio(0);

        // D layout: col = lm (o), row = lg*4 + rg (s within tile)
#pragma unroll
        for (int rg = 0; rg < 4; ++rg) {
            const int sr0 = (mp * 2 + 0) * 16 + lg * 4 + rg;
            const int sr1 = (mp * 2 + 1) * 16 + lg * 4 + rg;
            const float s0f = (float)sr0, s1f = (float)sr1;
            const float y0 = acc0[rg] + fmaf(s0f, fmaf(s0f, e2, e1), e0);
            const float y1 = acc1[rg] + fmaf(s1f, fmaf(s1f, e2, e1), e0);
            y[(((size_t)(c * 64 + sr0)) * 64 + bb) * 64 + o] = y0;
            y[(((size_t)(c * 64 + sr1)) * 64 + bb) * 64 + o] = y1;
        }
    }
}

// ---------------------------------------------------------------------------
extern "C" void kernel_launch(void* const* d_in, const int* in_sizes, int n_in,
                              void* d_out, int out_size, void* d_ws, size_t ws_size,
                              hipStream_t stream) {
    (void)in_sizes; (void)n_in; (void)out_size; (void)ws_size;

    const float* h0 = (const float*)d_in[0];   // [B, DH]
    const float* x  = (const float*)d_in[1];   // [T, B, DI]
    const float* a  = (const float*)d_in[2];   // [DH]
    const float* bm = (const float*)d_in[3];   // [DI, DH]
    const float* cm = (const float*)d_in[4];   // [DH, DO]

    float* out  = (float*)d_out;
    float* hfin = out;                         // [B, DH]
    float* y    = out + (size_t)B_ * DH_;      // [T, B, DO]

    float* r = (float*)d_ws;                   // [C,B,DH] f32 (8 MB), becomes Hst
    unsigned short* bhi  = (unsigned short*)(r + (size_t)C_ * B_ * DH_);
    unsigned short* be1  = bhi + 32768;
    unsigned short* be2  = be1 + 32768;
    unsigned short* CwEh = be2 + 32768;        // 98304
    unsigned short* CwEl = CwEh + 98304;       // 98304
    unsigned short* Dstk = CwEl + 98304;       // 12288
    unsigned short* Xm   = Dstk + 12288;       // [C][3][4096] bf16
    float* E = (float*)(Xm + (size_t)C_ * 3 * 4096);   // [4096][192] f32

    k_frags<<<dim3(384), 256, 0, stream>>>(bm, cm, a, bhi, be1, be2, CwEh, CwEl);
    k_D<<<dim3(192), 64, 0, stream>>>(bm, cm, a, Dstk);
    k_mom<<<dim3(C_, 16), 256, 0, stream>>>(x, Xm);
    k_rg<<<dim3(C_, 2), 512, 0, stream>>>(Xm, bhi, be1, be2, r);
    k_scan<<<dim3(B_), 512, 0, stream>>>(h0, a, r, hfin);
    k_E<<<dim3(C_, 3), 512, 0, stream>>>(r, CwEh, CwEl, E);
    k_y<<<dim3(C_, B_), 512, 0, stream>>>(x, Dstk, E, y);
}

// Round 15
// 101.548 us; speedup vs baseline: 1.5192x; 1.5192x over previous
//
#include <hip/hip_runtime.h>
#include <stdint.h>

// Problem constants
#define T_  4096
#define B_  64
#define DI_ 64
#define DH_ 512
#define DO_ 64
#define L_  64          // chunk length
#define C_  (T_ / L_)   // 64 chunks

typedef __attribute__((ext_vector_type(8))) short bf16x8;
typedef __attribute__((ext_vector_type(2))) float f32x2;
typedef __attribute__((ext_vector_type(4))) float f32x4;
typedef __attribute__((ext_vector_type(8))) float f32x8;
typedef __attribute__((ext_vector_type(2))) __bf16 bfv2;
typedef __attribute__((ext_vector_type(4))) __bf16 bfv4;
typedef __attribute__((ext_vector_type(8))) __bf16 bfv8;

union U8 { uint4 q; bf16x8 v; bfv8 b; };
union U2 { unsigned u; bfv2 b; };

__device__ inline unsigned short f2b_rne(float f) {
    unsigned u = __float_as_uint(f);
    return (unsigned short)((u + 0x7fffu + ((u >> 16) & 1u)) >> 16);
}

// trunc-split 8 f32 -> hi bf16x8 + lo bf16x8 (combined rel err ~2^-16)
__device__ inline void trunc_split8(const float4 v0, const float4 v1, U8& hi, U8& lo) {
    const unsigned u0 = __float_as_uint(v0.x), u1 = __float_as_uint(v0.y),
                   u2 = __float_as_uint(v0.z), u3 = __float_as_uint(v0.w),
                   u4 = __float_as_uint(v1.x), u5 = __float_as_uint(v1.y),
                   u6 = __float_as_uint(v1.z), u7 = __float_as_uint(v1.w);
    hi.q.x = __builtin_amdgcn_perm(u1, u0, 0x07060302u);
    hi.q.y = __builtin_amdgcn_perm(u3, u2, 0x07060302u);
    hi.q.z = __builtin_amdgcn_perm(u5, u4, 0x07060302u);
    hi.q.w = __builtin_amdgcn_perm(u7, u6, 0x07060302u);
    const unsigned l0 = __float_as_uint(v0.x - __uint_as_float(u0 & 0xffff0000u));
    const unsigned l1 = __float_as_uint(v0.y - __uint_as_float(u1 & 0xffff0000u));
    const unsigned l2 = __float_as_uint(v0.z - __uint_as_float(u2 & 0xffff0000u));
    const unsigned l3 = __float_as_uint(v0.w - __uint_as_float(u3 & 0xffff0000u));
    const unsigned l4 = __float_as_uint(v1.x - __uint_as_float(u4 & 0xffff0000u));
    const unsigned l5 = __float_as_uint(v1.y - __uint_as_float(u5 & 0xffff0000u));
    const unsigned l6 = __float_as_uint(v1.z - __uint_as_float(u6 & 0xffff0000u));
    const unsigned l7 = __float_as_uint(v1.w - __uint_as_float(u7 & 0xffff0000u));
    lo.q.x = __builtin_amdgcn_perm(l1, l0, 0x07060302u);
    lo.q.y = __builtin_amdgcn_perm(l3, l2, 0x07060302u);
    lo.q.z = __builtin_amdgcn_perm(l5, l4, 0x07060302u);
    lo.q.w = __builtin_amdgcn_perm(l7, l6, 0x07060302u);
}

// ---------------------------------------------------------------------------
// k_frags: (A) bhi/be1/be2 frags for k_rg; (B) CwE hi/lo frags for k_E;
// (C) u_arr[h] = logf(a[h]) for k_D. grid 384 x 256.
// ---------------------------------------------------------------------------
__global__ __launch_bounds__(256) void k_frags(
    const float* __restrict__ bmat, const float* __restrict__ cmat,
    const float* __restrict__ a,
    unsigned short* __restrict__ bhi, unsigned short* __restrict__ be1,
    unsigned short* __restrict__ be2,
    unsigned short* __restrict__ CwEh, unsigned short* __restrict__ CwEl,
    float* __restrict__ u_arr)
{
    const int t = blockIdx.x * 256 + threadIdx.x;   // 0..98303
    if (t < 512) u_arr[t] = logf(a[t]);
    if (t < 32768) {
        const int j = t & 7, n = (t >> 3) & 15, g = (t >> 7) & 3;
        const int nt = (t >> 9) & 31, kb = (t >> 14) & 1;
        const int h = nt * 16 + n;
        const float v = bmat[(size_t)(kb * 32 + g * 8 + j) * DH_ + h];
        const float u = logf(a[h]);
        bhi[t] = f2b_rne(v);
        be1[t] = f2b_rne(v * u);
        be2[t] = f2b_rne(v * u * u * 0.5f);
    }
    {
        const int j = t & 7;
        const int lane = (t >> 3) & 63;
        const int rem = t >> 9;             // 0..191
        const int nt = rem % 12, kb = rem / 12;
        const int h = kb * 32 + (lane >> 4) * 8 + j;
        const int n = nt * 16 + (lane & 15);
        const int m = n >> 6, o = n & 63;
        const float av = a[h];
        const float u = logf(av);
        const float w = (m == 0) ? av : ((m == 1) ? av * u : av * u * u * 0.5f);
        const float v = w * cmat[(size_t)h * DO_ + o];
        unsigned short hi16 = (unsigned short)(__float_as_uint(v) >> 16);
        float lo = v - __uint_as_float(((unsigned)hi16) << 16);
        CwEh[t] = hi16;
        CwEl[t] = (unsigned short)(__float_as_uint(lo) >> 16);
    }
}

// ---------------------------------------------------------------------------
// k_D (MFMA): D[kpos][o] = sum_h b[i(kpos)][h] * w_p(kpos)[h] * c[h][o].
// kpos<128: i=kpos>>1, p=kpos&1; else p=2, i=kpos-128. M=192, N=64, K=512.
// grid 12 x 256 (block = 16-row kpos tile, wave = 16-col o tile).
// Output written directly into Dstk B-frag layout (bf16).
// ---------------------------------------------------------------------------
__global__ __launch_bounds__(256) void k_D(
    const float* __restrict__ bmat, const float* __restrict__ cmat,
    const float* __restrict__ u_arr, unsigned short* __restrict__ Dstk)
{
    const int mt   = blockIdx.x;       // 0..11
    const int tid  = threadIdx.x;
    const int lane = tid & 63;
    const int nt   = tid >> 6;         // 0..3
    const int lm   = lane & 15;
    const int lg   = lane >> 4;

    const int kposr = mt * 16 + lm;    // A-frag row
    int p, i;
    if (kposr < 128) { i = kposr >> 1; p = kposr & 1; }
    else             { p = 2; i = kposr - 128; }

    f32x4 acc = {0.f, 0.f, 0.f, 0.f};
#pragma unroll
    for (int kb = 0; kb < 16; ++kb) {
        const int h0 = kb * 32 + lg * 8;
        const float4 b0 = *(const float4*)(bmat + (size_t)i * DH_ + h0);
        const float4 b1 = *(const float4*)(bmat + (size_t)i * DH_ + h0 + 4);
        const float4 w0 = *(const float4*)(u_arr + h0);
        const float4 w1 = *(const float4*)(u_arr + h0 + 4);
        const float bv[8] = {b0.x, b0.y, b0.z, b0.w, b1.x, b1.y, b1.z, b1.w};
        const float uv[8] = {w0.x, w0.y, w0.z, w0.w, w1.x, w1.y, w1.z, w1.w};
        U8 af, cf;
        bfv8 ab, cb;
#pragma unroll
        for (int j = 0; j < 8; ++j) {
            const float wp = (p == 0) ? 1.f : ((p == 1) ? uv[j] : uv[j] * uv[j] * 0.5f);
            ab[j] = (__bf16)(bv[j] * wp);
            cb[j] = (__bf16)cmat[(size_t)(h0 + j) * DO_ + nt * 16 + lm];
        }
        af.b = ab; cf.b = cb;
        acc = __builtin_amdgcn_mfma_f32_16x16x32_bf16(af.v, cf.v, acc, 0, 0, 0);
    }

    // D output: col = lm (o), row = lg*4 + rg (kpos within tile) -> Dstk frag
#pragma unroll
    for (int rg = 0; rg < 4; ++rg) {
        const int kpos = mt * 16 + lg * 4 + rg;
        const int o    = nt * 16 + lm;
        Dstk[((size_t)((kpos >> 5) * 4 + (o >> 4)) * 64 + ((kpos >> 3) & 3) * 16 + (o & 15)) * 8 + (kpos & 7)]
            = f2b_rne(acc[rg]);
    }
}

// ---------------------------------------------------------------------------
// k_mom: per-chunk moment reduction over x (streaming).
// ---------------------------------------------------------------------------
__global__ __launch_bounds__(256) void k_mom(
    const float* __restrict__ x, unsigned short* __restrict__ Xm)
{
    const int c   = blockIdx.x;
    const int idx = blockIdx.y * 256 + threadIdx.x;
    const float* xp = x + (size_t)c * 64 * 4096 + idx;

    float m0 = 0.f, m1 = 0.f, m2 = 0.f;
#pragma unroll
    for (int s = 0; s < 64; ++s) {
        const float v = xp[(size_t)s * 4096];
        const float t = (float)(63 - s);
        m0 += v;
        m1 = fmaf(t, v, m1);
        m2 = fmaf(t * t, v, m2);
    }
    __bf16* Xb = (__bf16*)Xm;
    Xb[(size_t)(c * 3 + 0) * 4096 + idx] = (__bf16)m0;
    Xb[(size_t)(c * 3 + 1) * 4096 + idx] = (__bf16)m1;
    Xb[(size_t)(c * 3 + 2) * 4096 + idx] = (__bf16)m2;
}

// ---------------------------------------------------------------------------
// k_rg: r[c][bb][h] = sum_k (u^k/k!)(X_k @ b)[h], one GEMM K=192 folded.
// ---------------------------------------------------------------------------
__global__ __launch_bounds__(512) void k_rg(
    const unsigned short* __restrict__ Xm,
    const unsigned short* __restrict__ bhi, const unsigned short* __restrict__ be1,
    const unsigned short* __restrict__ be2,
    float* __restrict__ r)
{
    const int c    = blockIdx.x;
    const int nh   = blockIdx.y;
    const int tid  = threadIdx.x;
    const int lane = tid & 63;
    const int w    = tid >> 6;
    const int lm   = lane & 15;
    const int lg   = lane >> 4;

    bf16x8 af[4][6];
#pragma unroll
    for (int mt = 0; mt < 4; ++mt)
#pragma unroll
        for (int kb = 0; kb < 6; ++kb) {
            const int mom = kb >> 1;
            af[mt][kb] = *(const bf16x8*)(Xm + (size_t)(c * 3 + mom) * 4096
                                          + (mt * 16 + lm) * 64 + (kb & 1) * 32 + lg * 8);
        }

    bf16x8 bfr[6][2];
#pragma unroll
    for (int kb = 0; kb < 6; ++kb) {
        const int mom = kb >> 1;
        const unsigned short* base = (mom == 0) ? bhi : (mom == 1) ? be1 : be2;
#pragma unroll
        for (int nt = 0; nt < 2; ++nt) {
            const int ntg = nh * 16 + w * 2 + nt;
            bfr[kb][nt] = *(const bf16x8*)(base + ((size_t)((kb & 1) * 32 + ntg) * 64 + lane) * 8);
        }
    }

    f32x4 acc[4][2];
#pragma unroll
    for (int mt = 0; mt < 4; ++mt)
#pragma unroll
        for (int nt = 0; nt < 2; ++nt) acc[mt][nt] = (f32x4){0.f, 0.f, 0.f, 0.f};

#pragma unroll
    for (int kb = 0; kb < 6; ++kb)
#pragma unroll
        for (int nt = 0; nt < 2; ++nt)
#pragma unroll
            for (int mt = 0; mt < 4; ++mt)
                acc[mt][nt] = __builtin_amdgcn_mfma_f32_16x16x32_bf16(af[mt][kb], bfr[kb][nt], acc[mt][nt], 0, 0, 0);

#pragma unroll
    for (int mt = 0; mt < 4; ++mt)
#pragma unroll
        for (int nt = 0; nt < 2; ++nt)
#pragma unroll
            for (int rg = 0; rg < 4; ++rg) {
                const int bb = mt * 16 + lg * 4 + rg;
                const int h  = nh * 256 + w * 32 + nt * 16 + lm;
                r[((size_t)c * B_ + bb) * DH_ + h] = acc[mt][nt][rg];
            }
}

// ---------------------------------------------------------------------------
// k_scan: sequential scan over chunk aggregates, IN PLACE (r becomes Hst).
// ---------------------------------------------------------------------------
__global__ __launch_bounds__(512) void k_scan(
    const float* __restrict__ h0, const float* __restrict__ a,
    float* __restrict__ r, float* __restrict__ hfin)
{
    const int bb  = blockIdx.x;
    const int hid = threadIdx.x;
    const size_t base = (size_t)bb * DH_ + hid;

    float rv[C_];
#pragma unroll
    for (int c = 0; c < C_; ++c) rv[c] = r[(size_t)c * B_ * DH_ + base];

    float h  = h0[base];
    float aL = a[hid];
#pragma unroll
    for (int q = 0; q < 6; ++q) aL = aL * aL;   // a^64

#pragma unroll
    for (int c = 0; c < C_; ++c) {
        r[(size_t)c * B_ * DH_ + base] = h;      // Hst[c]
        h = fmaf(h, aL, rv[c]);
    }
    hfin[base] = h;
}

// ---------------------------------------------------------------------------
// k_E: E[(c*64+bb)][n] = Hst row @ CwE  (M=4096, N=192, K=512), hi/lo 3-term.
// ---------------------------------------------------------------------------
__global__ __launch_bounds__(512) void k_E(
    const float* __restrict__ Hst,
    const unsigned short* __restrict__ CwEh, const unsigned short* __restrict__ CwEl,
    float* __restrict__ E)
{
    const int c    = blockIdx.x;
    const int nb   = blockIdx.y;            // 0..2
    const int tid  = threadIdx.x;
    const int lane = tid & 63;
    const int w    = tid >> 6;
    const int lm   = lane & 15;
    const int lg   = lane >> 4;
    const int mt   = w >> 1;
    const int ntp  = (w & 1) * 2;

    f32x4 acc[2] = {{0.f,0.f,0.f,0.f},{0.f,0.f,0.f,0.f}};

    for (int kb = 0; kb < 16; ++kb) {
        const float* ap = Hst + (size_t)(c * 64 + mt * 16 + lm) * DH_ + kb * 32 + lg * 8;
        U8 ahi, alo;
        trunc_split8(*(const float4*)ap, *(const float4*)(ap + 4), ahi, alo);
#pragma unroll
        for (int ntl = 0; ntl < 2; ++ntl) {
            const int ntg = nb * 4 + ntp + ntl;
            const size_t fo = ((size_t)(kb * 12 + ntg) * 64 + lane) * 8;
            const bf16x8 bh = *(const bf16x8*)(CwEh + fo);
            const bf16x8 bl = *(const bf16x8*)(CwEl + fo);
            acc[ntl] = __builtin_amdgcn_mfma_f32_16x16x32_bf16(ahi.v, bh, acc[ntl], 0, 0, 0);
            acc[ntl] = __builtin_amdgcn_mfma_f32_16x16x32_bf16(alo.v, bh, acc[ntl], 0, 0, 0);
            acc[ntl] = __builtin_amdgcn_mfma_f32_16x16x32_bf16(ahi.v, bl, acc[ntl], 0, 0, 0);
        }
    }

#pragma unroll
    for (int ntl = 0; ntl < 2; ++ntl)
#pragma unroll
        for (int rg = 0; rg < 4; ++rg) {
            const int row = mt * 16 + lg * 4 + rg;
            const int n   = (nb * 4 + ntp + ntl) * 16 + lm;
            E[(size_t)(c * 64 + row) * 192 + n] = acc[ntl][rg];
        }
}

// ---------------------------------------------------------------------------
// k_y: per (chunk, batch) block, 512 threads, static LDS 40960 B -> 3 blk/CU.
// ---------------------------------------------------------------------------
__global__ __launch_bounds__(512, 6) void k_y(
    const float* __restrict__ x,
    const unsigned short* __restrict__ Dstk,
    const float* __restrict__ E,
    float* __restrict__ y)
{
    __shared__ __align__(16) float xs[64 * 64];            // 16384 B
    __shared__ __align__(16) unsigned short At[64 * 192];  // 24576 B

    const int c    = blockIdx.x;
    const int bb   = blockIdx.y;
    const int tid  = threadIdx.x;
    const int lane = tid & 63;
    const int w    = tid >> 6;
    const int lm   = lane & 15;
    const int lg   = lane >> 4;
    const int mp   = w >> 2;
    const int oq   = w & 3;
    const int o    = oq * 16 + lm;

    const size_t erow = (size_t)(c * 64 + bb) * 192;
    const float e0 = E[erow + o];
    const float e1 = E[erow + 64 + o];
    const float e2 = E[erow + 128 + o];

    // ---- ph1: stage x chunk ----
    {
        const int row = tid >> 3;
        const int c8  = (tid & 7) * 8;
        const int c8x = c8 ^ ((row & 3) << 3);
        const float* gp = x + (((size_t)(c * 64 + row) * 64) + bb) * 64 + c8;
        const float4 v0 = *(const float4*)gp;
        const float4 v1 = *(const float4*)(gp + 4);
        *(float4*)&xs[row * 64 + c8x]     = v0;
        *(float4*)&xs[row * 64 + c8x + 4] = v1;
    }
    __syncthreads();

    // ---- ph2: prefix-moment scan (wave 0 only) ----
    if (tid < 64) {
        const int i = tid;
        float S0 = 0.f, S1 = 0.f, S2 = 0.f;
        char* Ab = (char*)At;
#pragma unroll
        for (int s = 0; s < 64; ++s) {
            const float v = xs[s * 64 + (i ^ ((s & 3) << 3))];
            const float sf = (float)s;
            S0 += v;
            S1 = fmaf(sf, v, S1);
            S2 = fmaf(sf * sf, v, S2);
            const float A0 = S0;
            const float A1 = fmaf(sf, S0, -S1);
            const float A2 = fmaf(sf, fmaf(sf, S0, -2.0f * S1), S2);
            const int f = (s & 7) << 4;
            U2 pk; pk.b = __builtin_convertvector((f32x2){A0, A1}, bfv2);
            *(unsigned*)(Ab + ((s * 384 + 4 * i) ^ f)) = pk.u;
            *(__bf16*)(Ab + ((s * 384 + 256 + 2 * i) ^ f)) = (__bf16)A2;
        }
    }
    __syncthreads();

    // ---- ph3: y = A @ D + E-term ----
    {
        const int row0 = (mp * 2 + 0) * 16 + lm;
        const int row1 = (mp * 2 + 1) * 16 + lm;
        const int f0 = (row0 & 7) << 4;
        const int f1 = (row1 & 7) << 4;
        const char* Ab = (const char*)At;

        f32x4 acc0 = {0.f, 0.f, 0.f, 0.f};
        f32x4 acc1 = {0.f, 0.f, 0.f, 0.f};

        __builtin_amdgcn_s_setprio(1);
#pragma unroll
        for (int kb = 0; kb < 6; ++kb) {
            const int b2k = kb * 64 + lg * 16;
            const bf16x8 a0 = *(const bf16x8*)(Ab + ((row0 * 384 + b2k) ^ f0));
            const bf16x8 a1 = *(const bf16x8*)(Ab + ((row1 * 384 + b2k) ^ f1));
            const bf16x8 df = *(const bf16x8*)(Dstk + ((size_t)(kb * 4 + oq) * 64 + lane) * 8);
            acc0 = __builtin_amdgcn_mfma_f32_16x16x32_bf16(a0, df, acc0, 0, 0, 0);
            acc1 = __builtin_amdgcn_mfma_f32_16x16x32_bf16(a1, df, acc1, 0, 0, 0);
        }
        __builtin_amdgcn_s_setprio(0);

#pragma unroll
        for (int rg = 0; rg < 4; ++rg) {
            const int sr0 = (mp * 2 + 0) * 16 + lg * 4 + rg;
            const int sr1 = (mp * 2 + 1) * 16 + lg * 4 + rg;
            const float s0f = (float)sr0, s1f = (float)sr1;
            const float y0 = acc0[rg] + fmaf(s0f, fmaf(s0f, e2, e1), e0);
            const float y1 = acc1[rg] + fmaf(s1f, fmaf(s1f, e2, e1), e0);
            y[(((size_t)(c * 64 + sr0)) * 64 + bb) * 64 + o] = y0;
            y[(((size_t)(c * 64 + sr1)) * 64 + bb) * 64 + o] = y1;
        }
    }
}

// ---------------------------------------------------------------------------
extern "C" void kernel_launch(void* const* d_in, const int* in_sizes, int n_in,
                              void* d_out, int out_size, void* d_ws, size_t ws_size,
                              hipStream_t stream) {
    (void)in_sizes; (void)n_in; (void)out_size; (void)ws_size;

    const float* h0 = (const float*)d_in[0];   // [B, DH]
    const float* x  = (const float*)d_in[1];   // [T, B, DI]
    const float* a  = (const float*)d_in[2];   // [DH]
    const float* bm = (const float*)d_in[3];   // [DI, DH]
    const float* cm = (const float*)d_in[4];   // [DH, DO]

    float* out  = (float*)d_out;
    float* hfin = out;                         // [B, DH]
    float* y    = out + (size_t)B_ * DH_;      // [T, B, DO]

    float* r = (float*)d_ws;                   // [C,B,DH] f32 (8 MB), becomes Hst
    unsigned short* bhi  = (unsigned short*)(r + (size_t)C_ * B_ * DH_);
    unsigned short* be1  = bhi + 32768;
    unsigned short* be2  = be1 + 32768;
    unsigned short* CwEh = be2 + 32768;        // 98304
    unsigned short* CwEl = CwEh + 98304;       // 98304
    unsigned short* Dstk = CwEl + 98304;       // 12288
    unsigned short* Xm   = Dstk + 12288;       // [C][3][4096] bf16
    float* E = (float*)(Xm + (size_t)C_ * 3 * 4096);   // [4096][192] f32
    float* u_arr = E + (size_t)4096 * 192;             // [512] f32

    k_frags<<<dim3(384), 256, 0, stream>>>(bm, cm, a, bhi, be1, be2, CwEh, CwEl, u_arr);
    k_D<<<dim3(12), 256, 0, stream>>>(bm, cm, u_arr, Dstk);
    k_mom<<<dim3(C_, 16), 256, 0, stream>>>(x, Xm);
    k_rg<<<dim3(C_, 2), 512, 0, stream>>>(Xm, bhi, be1, be2, r);
    k_scan<<<dim3(B_), 512, 0, stream>>>(h0, a, r, hfin);
    k_E<<<dim3(C_, 3), 512, 0, stream>>>(r, CwEh, CwEl, E);
    k_y<<<dim3(C_, B_), 512, 0, stream>>>(x, Dstk, E, y);
}